// Round 4
// baseline (178.933 us; speedup 1.0000x reference)
//
#include <hip/hip_runtime.h>

#define NN 1024
#define FF 128
#define NBLK 512

typedef __attribute__((ext_vector_type(8))) short bf16x8;
typedef __attribute__((ext_vector_type(4))) float f32x4;

__device__ __forceinline__ unsigned short f2bf(float x) {
  unsigned u = __float_as_uint(x);
  u += 0x7fff + ((u >> 16) & 1);   // round-to-nearest-even
  return (unsigned short)(u >> 16);
}
__device__ __forceinline__ float bf2f(unsigned short b) {
  return __uint_as_float(((unsigned)b) << 16);
}
__device__ __forceinline__ bf16x8 cvt8(float4 a, float4 b) {
  bf16x8 r;
  r[0] = (short)f2bf(a.x); r[1] = (short)f2bf(a.y);
  r[2] = (short)f2bf(a.z); r[3] = (short)f2bf(a.w);
  r[4] = (short)f2bf(b.x); r[5] = (short)f2bf(b.y);
  r[6] = (short)f2bf(b.z); r[7] = (short)f2bf(b.w);
  return r;
}

// async global->LDS, 16B per lane. LDS dest = wave-uniform base + lane*16.
__device__ __forceinline__ void gl_lds16(const void* g, void* l) {
  __builtin_amdgcn_global_load_lds(
      (const __attribute__((address_space(1))) unsigned*)g,
      (__attribute__((address_space(3))) unsigned*)l, 16, 0, 0);
}

// Grid barrier: all NBLK blocks co-resident (72KB LDS -> exactly 2/CU x 256CU).
// sync[0]=cnt, sync[1]=gen; zeroed by k_deg (stream order). __syncthreads()
// first: drains vmcnt (keeps agg's counted-vmcnt exact) + joins block.
// AGENT-scope acq_rel: release writes back L2 (Yt visible cross-XCD),
// acquire invalidates caches on exit.
__device__ __forceinline__ void gsync(unsigned* sync) {
  __syncthreads();
  if (threadIdx.x == 0) {
    unsigned g0 = __hip_atomic_load(&sync[1], __ATOMIC_RELAXED,
                                    __HIP_MEMORY_SCOPE_AGENT);
    unsigned my = __hip_atomic_fetch_add(&sync[0], 1u, __ATOMIC_ACQ_REL,
                                         __HIP_MEMORY_SCOPE_AGENT);
    if (my == NBLK - 1) {
      __hip_atomic_store(&sync[0], 0u, __ATOMIC_RELAXED,
                         __HIP_MEMORY_SCOPE_AGENT);
      __hip_atomic_fetch_add(&sync[1], 1u, __ATOMIC_RELEASE,
                             __HIP_MEMORY_SCOPE_AGENT);
    } else {
      while (__hip_atomic_load(&sync[1], __ATOMIC_ACQUIRE,
                               __HIP_MEMORY_SCOPE_AGENT) == g0)
        __builtin_amdgcn_s_sleep(2);
    }
  }
  __syncthreads();
}

// ---------------------------------------------------------------------------
// K1: deg[b,n] = 1 + sum_m A[b,n,m]; d = rsqrt(deg). One wave per row.
// Pure read — leaves A L3-resident. Tail blocks build Wt[g][f] = bf16(W[f][g]).
// Block 4096 also zeroes the grid-sync counters for k_fused.
// ---------------------------------------------------------------------------
__global__ __launch_bounds__(256) void k_deg(const float* __restrict__ A,
                                             const float* __restrict__ W,
                                             float* __restrict__ d,
                                             unsigned short* __restrict__ Wt,
                                             unsigned* __restrict__ sync) {
  if (blockIdx.x >= 4096) {
    if (blockIdx.x == 4096 && threadIdx.x < 2) sync[threadIdx.x] = 0u;
    int id = (blockIdx.x - 4096) * 256 + threadIdx.x;
    int g = id >> 7, f = id & 127;
    Wt[g * 128 + f] = f2bf(W[f * 128 + g]);
    return;
  }
  int row  = blockIdx.x * 4 + (threadIdx.x >> 6);
  int lane = threadIdx.x & 63;
  const float4* Ar = (const float4*)(A + (size_t)row * NN);
  float s = 0.f;
#pragma unroll
  for (int i = 0; i < 4; ++i) {
    float4 v = Ar[lane + i * 64];
    s += (v.x + v.y) + (v.z + v.w);
  }
#pragma unroll
  for (int off = 32; off > 0; off >>= 1) s += __shfl_down(s, off, 64);
  if (lane == 0) d[row] = rsqrtf(s + 1.0f);
}

// ---------------------------------------------------------------------------
// K2 fused: phase XW (Yt[b][g][m] = bf16(d_m * (XW)[m,g])) -> grid barrier ->
// phase AGG (out[b,n,g] = d_n * (sum_m A[n,m]*Yt[g,m] + Yt[g,n])).
// 512 blocks x 256 thr, 72KB LDS (2 blocks/CU, all co-resident for gsync).
// XW: 256 tile-jobs (b,m0) x 2 g-halves; each block: 64 m x 64 g.
// AGG: identical to the verified Round-3 k_agg (BM=32,BN=128,BK=64, triple-
// buffered, counted vmcnt(6), one s_barrier/stage, setprio on MFMA cluster).
// ---------------------------------------------------------------------------
__global__ __launch_bounds__(256, 2) void k_fused(const float* __restrict__ X,
                                                  const float* __restrict__ A,
                                                  const unsigned short* __restrict__ Wt,
                                                  const float* __restrict__ d,
                                                  unsigned short* __restrict__ Yt,
                                                  float* __restrict__ out,
                                                  unsigned* __restrict__ sync) {
  __shared__ __align__(16) char smem[73728];   // 72 KB, phase-aliased
  int t = threadIdx.x;
  int bid = blockIdx.x;
  int wave = t >> 6, lane = t & 63, quad = lane >> 4, l16 = lane & 15;

  // ================= phase XW =================
  {
    unsigned short* Xs = (unsigned short*)smem;              // 64*128 = 16KB
    unsigned short* Ws = (unsigned short*)(smem + 16384);    // 64*128 = 16KB
    float*          dl = (float*)(smem + 32768);             // 64 floats
    int job = bid >> 1, gh = bid & 1;
    int xb = job >> 4, m0 = (job & 15) * 64;

#pragma unroll
    for (int j = 0; j < 4; ++j) {
      int id = t + j * 256;
      int r = id >> 4, p = id & 15, c = p ^ (r & 15);
      const float* gp = X + ((size_t)(xb * NN + m0 + r) * FF + c * 8);
      float4 v0 = *(const float4*)gp;
      float4 v1 = *(const float4*)(gp + 4);
      *(bf16x8*)&Xs[r * 128 + p * 8] = cvt8(v0, v1);
    }
#pragma unroll
    for (int j = 0; j < 4; ++j) {
      int id = t + j * 256;
      int gl = id >> 4, p = id & 15, c = p ^ (gl & 15);
      uint4 v = *(const uint4*)(Wt + (size_t)(gh * 64 + gl) * 128 + c * 8);
      *(uint4*)&Ws[gl * 128 + p * 8] = v;
    }
    if (t < 64) dl[t] = d[xb * NN + m0 + t];
    __syncthreads();

    f32x4 acc[4];
#pragma unroll
    for (int ct = 0; ct < 4; ++ct) acc[ct] = (f32x4){0.f, 0.f, 0.f, 0.f};
#pragma unroll
    for (int ks = 0; ks < 4; ++ks) {
      int q = ks * 4 + quad;
      bf16x8 a = *(const bf16x8*)&Xs[(wave * 16 + l16) * 128 + (q ^ l16) * 8];
#pragma unroll
      for (int ct = 0; ct < 4; ++ct) {
        bf16x8 w = *(const bf16x8*)&Ws[(ct * 16 + l16) * 128 + (q ^ l16) * 8];
        acc[ct] = __builtin_amdgcn_mfma_f32_16x16x32_bf16(a, w, acc[ct], 0, 0, 0);
      }
    }
    int mb = wave * 16 + quad * 4;
    float4 d4 = *(const float4*)&dl[mb];
#pragma unroll
    for (int ct = 0; ct < 4; ++ct) {
      int g = gh * 64 + ct * 16 + l16;
      ushort4 p;
      p.x = f2bf(d4.x * acc[ct][0]);
      p.y = f2bf(d4.y * acc[ct][1]);
      p.z = f2bf(d4.z * acc[ct][2]);
      p.w = f2bf(d4.w * acc[ct][3]);
      *(ushort4*)(Yt + (size_t)(xb * 128 + g) * NN + m0 + mb) = p;
    }
  }

  gsync(sync);   // Yt complete & visible device-wide

  // ================= phase AGG =================
  {
    float*          Asf = (float*)smem;                      // [3][32*64] 24KB
    unsigned short* Ys  = (unsigned short*)(smem + 24576);   // [3][128*64] 48KB
    int xcd = bid & 7;
    int j   = bid >> 3;
    int b   = xcd + 8 * (j >> 5);
    int n0  = (j & 31) * 32;
    int wr = wave >> 1, wc = wave & 1;

    const float*          Ab = A  + (size_t)(b * NN + n0) * NN;
    const unsigned short* Yb = Yt + (size_t)b * 128 * NN;

    int ra = lane >> 4, pa_s = lane & 15;     // A staging
    int ry_s = lane >> 3, py_s = lane & 7;    // Y staging

    auto issue = [&](int k0, int bufi) {
#pragma unroll
      for (int jj = 0; jj < 2; ++jj) {
        int r = wave * 8 + jj * 4 + ra;
        int c = pa_s ^ (2 * (r & 7));
        gl_lds16(Ab + ((size_t)r * NN + k0 + c * 4),
                 &Asf[bufi * 2048 + (wave * 8 + jj * 4) * 64]);
      }
#pragma unroll
      for (int jj = 0; jj < 4; ++jj) {
        int ry = wave * 32 + jj * 8 + ry_s;
        int c  = py_s ^ (ry & 7);
        gl_lds16(Yb + ((size_t)ry * NN + k0 + c * 8),
                 &Ys[bufi * 8192 + (wave * 32 + jj * 8) * 64]);
      }
    };

    f32x4 acc[4];
#pragma unroll
    for (int ct = 0; ct < 4; ++ct) acc[ct] = (f32x4){0.f, 0.f, 0.f, 0.f};

    int swA = 2 * (l16 & 7);
    issue(0, 0);
    issue(64, 1);

#pragma unroll
    for (int s = 0; s < 16; ++s) {
      if (s < 15) asm volatile("s_waitcnt vmcnt(6)" ::: "memory");
      else        asm volatile("s_waitcnt vmcnt(0)" ::: "memory");
      __builtin_amdgcn_s_barrier();
      const float*          as = &Asf[(s % 3) * 2048];
      const unsigned short* ys = &Ys[(s % 3) * 8192];
      __builtin_amdgcn_s_setprio(1);
#pragma unroll
      for (int ks = 0; ks < 2; ++ks) {
        int cq = ks * 4 + quad;
        int pa = (2 * cq) ^ swA;
        float4 a0 = *(const float4*)&as[(wr * 16 + l16) * 64 + pa * 4];
        float4 a1 = *(const float4*)&as[(wr * 16 + l16) * 64 + pa * 4 + 4];
        bf16x8 a = cvt8(a0, a1);
#pragma unroll
        for (int ct = 0; ct < 4; ++ct) {
          int cp = (cq ^ (l16 & 7)) * 8;
          bf16x8 y = *(const bf16x8*)&ys[(wc * 64 + ct * 16 + l16) * 64 + cp];
          acc[ct] = __builtin_amdgcn_mfma_f32_16x16x32_bf16(a, y, acc[ct], 0, 0, 0);
        }
      }
      __builtin_amdgcn_s_setprio(0);
      __builtin_amdgcn_sched_barrier(0);
      if (s < 14) issue((s + 2) * 64, (s + 2) % 3);
    }

    int nb = n0 + wr * 16 + quad * 4;
    float4 d4 = *(const float4*)(d + b * NN + nb);
#pragma unroll
    for (int ct = 0; ct < 4; ++ct) {
      int g = wc * 64 + ct * 16 + l16;
      ushort4 yv = *(const ushort4*)(Yt + (size_t)(b * 128 + g) * NN + nb);
      float* op = out + ((size_t)(b * NN + nb) * FF + g);
      op[0 * FF] = d4.x * (acc[ct][0] + bf2f(yv.x));
      op[1 * FF] = d4.y * (acc[ct][1] + bf2f(yv.y));
      op[2 * FF] = d4.z * (acc[ct][2] + bf2f(yv.z));
      op[3 * FF] = d4.w * (acc[ct][3] + bf2f(yv.w));
    }
  }
}

// ---------------------------------------------------------------------------
extern "C" void kernel_launch(void* const* d_in, const int* in_sizes, int n_in,
                              void* d_out, int out_size, void* d_ws, size_t ws_size,
                              hipStream_t stream) {
  const float* X = (const float*)d_in[0];  // [16,1024,128]
  const float* A = (const float*)d_in[1];  // [16,1024,1024]
  const float* W = (const float*)d_in[2];  // [128,128]
  float* out = (float*)d_out;              // [16,1024,128]

  char* ws = (char*)d_ws;
  float*          dinv = (float*)ws;                    // 64 KB
  unsigned short* Wt   = (unsigned short*)(ws + 65536); // 32 KB
  unsigned short* Yt   = (unsigned short*)(ws + 98304); // 4 MB [b][g][m]
  unsigned*       sync = (unsigned*)(ws + 4292608);     // 2 x u32, zeroed by k_deg

  k_deg  <<<dim3(4096 + 64), dim3(256), 0, stream>>>(A, W, dinv, Wt, sync);
  k_fused<<<dim3(NBLK),      dim3(256), 0, stream>>>(X, A, Wt, dinv, Yt, out, sync);
}

// Round 7
// 117.489 us; speedup vs baseline: 1.5230x; 1.5230x over previous
//
#include <hip/hip_runtime.h>

#define NN 1024
#define FF 128

typedef __attribute__((ext_vector_type(8))) short bf16x8;
typedef __attribute__((ext_vector_type(4))) float f32x4;

__device__ __forceinline__ unsigned short f2bf(float x) {
  unsigned u = __float_as_uint(x);
  u += 0x7fff + ((u >> 16) & 1);   // round-to-nearest-even
  return (unsigned short)(u >> 16);
}
__device__ __forceinline__ float bf2f(unsigned short b) {
  return __uint_as_float(((unsigned)b) << 16);
}
__device__ __forceinline__ bf16x8 cvt8(float4 a, float4 b) {
  bf16x8 r;
  r[0] = (short)f2bf(a.x); r[1] = (short)f2bf(a.y);
  r[2] = (short)f2bf(a.z); r[3] = (short)f2bf(a.w);
  r[4] = (short)f2bf(b.x); r[5] = (short)f2bf(b.y);
  r[6] = (short)f2bf(b.z); r[7] = (short)f2bf(b.w);
  return r;
}

// async global->LDS, 16B per lane. LDS dest = wave-uniform base + lane*16.
__device__ __forceinline__ void gl_lds16(const void* g, void* l) {
  __builtin_amdgcn_global_load_lds(
      (const __attribute__((address_space(1))) unsigned*)g,
      (__attribute__((address_space(3))) unsigned*)l, 16, 0, 0);
}

// ---------------------------------------------------------------------------
// K1: two independent block families in ONE dispatch (concurrent):
//  blocks 0..255    : Yt[b][g][m] = bf16( sum_f X[b,m,f] W[f,g] )  (UNSCALED;
//                     d moved into k_agg). W transposed in-block via LDS
//                     scatter — no Wt prepass, no d dependency.
//  blocks 256..4351 : deg[b,n] = 1 + sum_m A[b,n,m]; d = rsqrt(deg).
//                     One wave per row; BW-bound (64 MiB) — XW hides under it.
// ---------------------------------------------------------------------------
__global__ __launch_bounds__(256) void k_degxw(const float* __restrict__ A,
                                               const float* __restrict__ X,
                                               const float* __restrict__ W,
                                               float* __restrict__ d,
                                               unsigned short* __restrict__ Yt) {
  if (blockIdx.x >= 256) {               // ---- deg family ----
    int row  = (blockIdx.x - 256) * 4 + (threadIdx.x >> 6);
    int lane = threadIdx.x & 63;
    const float4* Ar = (const float4*)(A + (size_t)row * NN);
    float s = 0.f;
#pragma unroll
    for (int i = 0; i < 4; ++i) {
      float4 v = Ar[lane + i * 64];
      s += (v.x + v.y) + (v.z + v.w);
    }
#pragma unroll
    for (int off = 32; off > 0; off >>= 1) s += __shfl_down(s, off, 64);
    if (lane == 0) d[row] = rsqrtf(s + 1.0f);
    return;
  }

  // ---- XW family: 64 m-rows x 128 g per block ----
  __shared__ __align__(16) unsigned short Xs[64 * 128];    // 16KB
  __shared__ __align__(16) unsigned short Ws[128 * 128];   // 32KB
  int t  = threadIdx.x;
  int b  = blockIdx.x >> 4;
  int m0 = (blockIdx.x & 15) * 64;

  // X tile: coalesced float4 pairs -> bf16, XOR-swizzled (verified layout)
#pragma unroll
  for (int j = 0; j < 4; ++j) {
    int id = t + j * 256;
    int r = id >> 4, p = id & 15, c = p ^ (r & 15);
    const float* gp = X + ((size_t)(b * NN + m0 + r) * FF + c * 8);
    float4 v0 = *(const float4*)gp;
    float4 v1 = *(const float4*)(gp + 4);
    *(bf16x8*)&Xs[r * 128 + p * 8] = cvt8(v0, v1);
  }
  // W transpose in-LDS: thread t owns row f = t>>1, g-half (t&1)*64.
  // Ws[g*128 + (c^(g&15))*8 + (f&7)] = bf16(W[f][g]), c = f>>3 — identical
  // final layout to the verified Wt-staged version.
  {
    int f = t >> 1, gh = (t & 1) * 64;
    const float* wrow = W + (size_t)f * FF + gh;
    int c8 = (f >> 3);
    int e  = f & 7;
#pragma unroll
    for (int j4 = 0; j4 < 16; ++j4) {
      float4 wv = *(const float4*)(wrow + j4 * 4);
#pragma unroll
      for (int k = 0; k < 4; ++k) {
        int g = gh + j4 * 4 + k;
        float v = (k == 0) ? wv.x : (k == 1) ? wv.y : (k == 2) ? wv.z : wv.w;
        Ws[g * 128 + ((c8 ^ (g & 15)) * 8) + e] = f2bf(v);
      }
    }
  }
  __syncthreads();

  int wave = t >> 6, lane = t & 63, quad = lane >> 4, l16 = lane & 15;
  f32x4 acc[8];
#pragma unroll
  for (int ct = 0; ct < 8; ++ct) acc[ct] = (f32x4){0.f, 0.f, 0.f, 0.f};

#pragma unroll
  for (int ks = 0; ks < 4; ++ks) {
    int q = ks * 4 + quad;
    bf16x8 a = *(const bf16x8*)&Xs[(wave * 16 + l16) * 128 + (q ^ l16) * 8];
#pragma unroll
    for (int ct = 0; ct < 8; ++ct) {
      bf16x8 w = *(const bf16x8*)&Ws[(ct * 16 + l16) * 128 + (q ^ l16) * 8];
      acc[ct] = __builtin_amdgcn_mfma_f32_16x16x32_bf16(a, w, acc[ct], 0, 0, 0);
    }
  }

  int mb = wave * 16 + quad * 4;
#pragma unroll
  for (int ct = 0; ct < 8; ++ct) {
    int g = ct * 16 + l16;
    ushort4 p;
    p.x = f2bf(acc[ct][0]);
    p.y = f2bf(acc[ct][1]);
    p.z = f2bf(acc[ct][2]);
    p.w = f2bf(acc[ct][3]);
    *(ushort4*)(Yt + (size_t)(b * 128 + g) * NN + m0 + mb) = p;
  }
}

// ---------------------------------------------------------------------------
// K2: out[b,n,g] = d_n * ( sum_m A[b,n,m]*d_m*Yt[b,g,m] + d_n*Yt[b,g,n] )
// Verified Round-3 pipeline: BM=32, BN=128, BK=64, 16 stages, TRIPLE-buffered
// (counted vmcnt(6), one s_barrier/stage, setprio on MFMA cluster). New: d[b,*]
// staged to LDS once; d_m folded into A fragments before cvt8 (Yt unscaled);
// epilogue applies d_n and d_n^2 on the identity term. LDS 76KB -> 2 blocks/CU.
// XCD swizzle keeps each batch's Yt L2-resident.
// ---------------------------------------------------------------------------
__global__ __launch_bounds__(256) void k_agg(const float* __restrict__ A,
                                             const unsigned short* __restrict__ Yt,
                                             const float* __restrict__ d,
                                             float* __restrict__ out) {
  __shared__ __align__(16) float          Asf[3][32 * 64];    // 3 x 8KB fp32
  __shared__ __align__(16) unsigned short Ys[3][128 * 64];    // 3 x 16KB bf16
  __shared__ __align__(16) float          dl[NN];             // 4KB: d[b][*]
  int t   = threadIdx.x;
  int bid = blockIdx.x;
  int xcd = bid & 7;
  int j   = bid >> 3;                    // 0..63
  int b   = xcd + 8 * (j >> 5);          // all 32 blocks of batch b on one XCD
  int n0  = (j & 31) * 32;
  int wave = t >> 6, lane = t & 63, quad = lane >> 4, l16 = lane & 15;
  int wr = wave >> 1, wc = wave & 1;

  const float*          Ab = A  + (size_t)(b * NN + n0) * NN;
  const unsigned short* Yb = Yt + (size_t)b * 128 * NN;

  // stage d[b][0..1023] into LDS (read by all stages + epilogue)
  *(float4*)&dl[t * 4] = *(const float4*)(d + (size_t)b * NN + t * 4);
  __syncthreads();

  int ra = lane >> 4, pa_s = lane & 15;     // A staging
  int ry_s = lane >> 3, py_s = lane & 7;    // Y staging

  auto issue = [&](int k0, int bufi) {
#pragma unroll
    for (int jj = 0; jj < 2; ++jj) {
      int r = wave * 8 + jj * 4 + ra;
      int c = pa_s ^ (2 * (r & 7));
      gl_lds16(Ab + ((size_t)r * NN + k0 + c * 4), &Asf[bufi][(wave * 8 + jj * 4) * 64]);
    }
#pragma unroll
    for (int jj = 0; jj < 4; ++jj) {
      int ry = wave * 32 + jj * 8 + ry_s;
      int c  = py_s ^ (ry & 7);
      gl_lds16(Yb + ((size_t)ry * NN + k0 + c * 8), &Ys[bufi][(wave * 32 + jj * 8) * 64]);
    }
  };

  f32x4 acc[4];
#pragma unroll
  for (int ct = 0; ct < 4; ++ct) acc[ct] = (f32x4){0.f, 0.f, 0.f, 0.f};

  int swA = 2 * (l16 & 7);               // even XOR key for A-frag positions
  issue(0, 0);
  issue(64, 1);

#pragma unroll
  for (int s = 0; s < 16; ++s) {
    if (s < 15) asm volatile("s_waitcnt vmcnt(6)" ::: "memory");
    else        asm volatile("s_waitcnt vmcnt(0)" ::: "memory");
    __builtin_amdgcn_s_barrier();        // stage-s tile ready for all waves
    const float*          as = &Asf[s % 3][0];
    const unsigned short* ys = &Ys[s % 3][0];
    int k0 = s * 64;
    __builtin_amdgcn_s_setprio(1);
#pragma unroll
    for (int ks = 0; ks < 2; ++ks) {
      int cq = ks * 4 + quad;            // k-chunk (8 floats) of this quad
      int pa = (2 * cq) ^ swA;           // stored 16B-chunk position
      float4 a0 = *(const float4*)&as[(wr * 16 + l16) * 64 + pa * 4];
      float4 a1 = *(const float4*)&as[(wr * 16 + l16) * 64 + pa * 4 + 4];
      float4 dv0 = *(const float4*)&dl[k0 + cq * 8];
      float4 dv1 = *(const float4*)&dl[k0 + cq * 8 + 4];
      a0.x *= dv0.x; a0.y *= dv0.y; a0.z *= dv0.z; a0.w *= dv0.w;
      a1.x *= dv1.x; a1.y *= dv1.y; a1.z *= dv1.z; a1.w *= dv1.w;
      bf16x8 a = cvt8(a0, a1);
#pragma unroll
      for (int ct = 0; ct < 4; ++ct) {
        int cp = (cq ^ (l16 & 7)) * 8;
        bf16x8 y = *(const bf16x8*)&ys[(wc * 64 + ct * 16 + l16) * 64 + cp];
        acc[ct] = __builtin_amdgcn_mfma_f32_16x16x32_bf16(a, y, acc[ct], 0, 0, 0);
      }
    }
    __builtin_amdgcn_s_setprio(0);
    __builtin_amdgcn_sched_barrier(0);
    if (s < 14) issue((s + 2) * 64, (s + 2) % 3);
  }

  // epilogue: out[n,g] = d_n*(acc + d_n*Y[g][n]); C/D: row=quad*4+reg, col=l16
  int nb = n0 + wr * 16 + quad * 4;
  float4 d4 = *(const float4*)&dl[nb];
#pragma unroll
  for (int ct = 0; ct < 4; ++ct) {
    int g = wc * 64 + ct * 16 + l16;
    ushort4 yv = *(const ushort4*)(Yt + (size_t)(b * 128 + g) * NN + nb);
    float* op = out + ((size_t)(b * NN + nb) * FF + g);
    op[0 * FF] = d4.x * (acc[ct][0] + d4.x * bf2f(yv.x));
    op[1 * FF] = d4.y * (acc[ct][1] + d4.y * bf2f(yv.y));
    op[2 * FF] = d4.z * (acc[ct][2] + d4.z * bf2f(yv.z));
    op[3 * FF] = d4.w * (acc[ct][3] + d4.w * bf2f(yv.w));
  }
}

// ---------------------------------------------------------------------------
extern "C" void kernel_launch(void* const* d_in, const int* in_sizes, int n_in,
                              void* d_out, int out_size, void* d_ws, size_t ws_size,
                              hipStream_t stream) {
  const float* X = (const float*)d_in[0];  // [16,1024,128]
  const float* A = (const float*)d_in[1];  // [16,1024,1024]
  const float* W = (const float*)d_in[2];  // [128,128]
  float* out = (float*)d_out;              // [16,1024,128]

  char* ws = (char*)d_ws;
  float*          dinv = (float*)ws;                    // 64 KB
  unsigned short* Yt   = (unsigned short*)(ws + 65536); // 4 MB [b][g][m]

  k_degxw<<<dim3(256 + 4096), dim3(256), 0, stream>>>(A, X, W, dinv, Yt);
  k_agg  <<<dim3(512),        dim3(256), 0, stream>>>(A, Yt, dinv, out);
}